// Round 17
// baseline (1187.796 us; speedup 1.0000x reference)
//
#include <hip/hip_runtime.h>
#include <math.h>

#define Bq 16
#define Lq 4096
#define Hq 256
#define Nq 64
#define NBq 4
#define F2q 512
#define BLq (Bq*Lq)

typedef __attribute__((ext_vector_type(8))) short short8;
typedef __attribute__((ext_vector_type(4))) float f32x4;

__device__ __forceinline__ unsigned short f2bf(float f){
  unsigned u = __float_as_uint(f);
  u = (u + 0x7fffu + ((u >> 16) & 1u)) >> 16;
  return (unsigned short)u;
}
__device__ __forceinline__ float bf2f(unsigned short u){
  return __uint_as_float(((unsigned)u) << 16);
}
// tanh-approx GELU (max abs err ~3e-4, well under bf16 rounding)
__device__ __forceinline__ float gelu(float x){
  float u = 0.79788456f*x*(1.f + 0.044715f*x*x);
  float t = 1.f - __fdividef(2.f, 1.f + __expf(2.f*fabsf(u)));
  return 0.5f*x*(1.f + copysignf(t, u));
}

__device__ __forceinline__ void stage16(const void* g, void* l){
  __builtin_amdgcn_global_load_lds((const __attribute__((address_space(1))) void*)g,
                                   (__attribute__((address_space(3))) void*)l, 16, 0, 0);
}

// ---------------- conv stem + fused LN stats: h[b][c][l] (bf16), mu, rstd ----
__global__ __launch_bounds__(256) void k_convln(const float* __restrict__ x,
    const float* __restrict__ cw, const float* __restrict__ cb,
    unsigned short* __restrict__ h, float* __restrict__ mu, float* __restrict__ rstd){
  __shared__ float xs[260];
  __shared__ float cwS[Hq*5];
  __shared__ float cbS[Hq];
  const int b = blockIdx.x >> 4;
  const int l0 = (blockIdx.x & 15) * 256;
  const int tid = threadIdx.x;
  for (int i=tid; i<Hq*5; i+=256) cwS[i] = cw[i];
  cbS[tid] = cb[tid];
  {
    int gl = l0 + tid - 2;
    xs[tid] = (gl>=0 && gl<Lq) ? x[(size_t)b*Lq + gl] : 0.f;
    if (tid < 4){
      int gl2 = l0 + 254 + tid;
      xs[256+tid] = (gl2>=0 && gl2<Lq) ? x[(size_t)b*Lq + gl2] : 0.f;
    }
  }
  __syncthreads();
  float s0=0.f, s1=0.f;
  unsigned short* hp = h + (size_t)b*Hq*Lq + l0 + tid;
  for (int c=0;c<Hq;c++){
    float acc = cbS[c];
    #pragma unroll
    for (int k=0;k<5;k++) acc = fmaf(cwS[c*5+k], xs[tid+k], acc);
    hp[(size_t)c*Lq] = f2bf(acc);
    s0 += acc; s1 = fmaf(acc, acc, s1);
  }
  int col = b*Lq + l0 + tid;
  float m = s0 * (1.0f/256.0f);
  float var = s1*(1.0f/256.0f) - m*m;
  mu[col] = m;
  rstd[col] = rsqrtf(fmaxf(var, 0.f) + 1e-5f);
}

// ---------------- S4D param precompute ----------------
__global__ __launch_bounds__(256) void k_s4pre(const float* __restrict__ log_dt,
    const float* __restrict__ lar, const float* __restrict__ aim,
    const float* __restrict__ cre, const float* __restrict__ cim,
    float* __restrict__ wre, float* __restrict__ wim,
    float* __restrict__ c2re, float* __restrict__ c2im){
  int idx = blockIdx.x*256 + threadIdx.x;           // NB*H*N
  int hh = (idx >> 6) & (Hq-1);
  int i = idx >> 14;
  float dt = expf(log_dt[i*Hq + hh]);
  float are = -expf(lar[idx]);
  float ai  = aim[idx];
  float dre = are*dt, dim = ai*dt;
  float er = expf(dre);
  float wr = er*cosf(dim), wi = er*sinf(dim);
  float nr = wr - 1.f, ni = wi;
  float den = are*are + ai*ai;
  float qre = (nr*are + ni*ai)/den;
  float qim = (ni*are - nr*ai)/den;
  float Cr = cre[idx], Ci = cim[idx];
  float cer = Cr*qre - Ci*qim;
  float cei = Cr*qim + Ci*qre;
  wre[idx] = wr; wim[idx] = wi;
  c2re[idx] = 2.f*cer; c2im[idx] = 2.f*cei;
}

// ---------------- weights -> bf16 ----------------
__global__ __launch_bounds__(256) void k_cvtw(const float* __restrict__ s0,
    const float* __restrict__ s1, const float* __restrict__ s2,
    unsigned short* __restrict__ d0, unsigned short* __restrict__ d1,
    unsigned short* __restrict__ d2){
  int idx = blockIdx.x*256 + threadIdx.x;
  d0[idx] = f2bf(s0[idx]);
  d1[idx] = f2bf(s1[idx]);
  d2[idx] = f2bf(s2[idx]);
}

// ---- per-(block,ch) matrices (ALL blocks): G=[T | interleave(Ere,-Eim)], Wbar, w64 ----
__global__ __launch_bounds__(64) void k_s4mat(const float* __restrict__ wre_,
    const float* __restrict__ wim_, const float* __restrict__ c2re_,
    const float* __restrict__ c2im_, const float* __restrict__ Dp,
    unsigned short* __restrict__ G, unsigned short* __restrict__ Wb,
    float* __restrict__ w64re_, float* __restrict__ w64im_){
  __shared__ float Kv[64];
  const int n = threadIdx.x;
  const int bcid = blockIdx.x;              // ib*256 + ch, 0..NB*H-1
  const int pidx = bcid*64 + n;
  const float wr = wre_[pidx], wi = wim_[pidx];
  const float cr = c2re_[pidx], ci = c2im_[pidx];
  unsigned short* Gb = G + (size_t)bcid*64*192;
  unsigned short* Wbb = Wb + (size_t)bcid*128*64;
  float pre = 1.f, pim = 0.f;
  for (int t=0;t<64;t++){
    float a = cr*pre - ci*pim;
    #pragma unroll
    for (int m=1;m<64;m<<=1) a += __shfl_xor(a, m, 64);
    if (n==0) Kv[t] = a;
    Wbb[n*64 + (63-t)] = f2bf(pre);
    Wbb[(64+n)*64 + (63-t)] = f2bf(pim);
    float qre = pre*wr - pim*wi;
    float qim = pre*wi + pim*wr;
    unsigned pk = (unsigned)f2bf(cr*qre - ci*qim)
                | ((unsigned)f2bf(-(cr*qim + ci*qre)) << 16);
    *(unsigned*)&Gb[t*192 + 64 + 2*n] = pk;   // interleaved (Ere, -Eim)
    pre = qre; pim = qim;
  }
  w64re_[pidx] = pre; w64im_[pidx] = pim;
  __syncthreads();
  float dv = Dp[bcid];
  for (int t=0;t<64;t++){
    float kv = (n<=t) ? Kv[t-n] : 0.f;
    if (n==t) kv += dv;
    Gb[t*192 + n] = f2bf(kv);
  }
}

// ---------------- finalize LN stats from two partial buffers ----------------
__global__ __launch_bounds__(256) void k_lnfin(const float2* __restrict__ st0,
    const float2* __restrict__ st1, float* __restrict__ mu, float* __restrict__ rstd){
  int col = blockIdx.x*256 + threadIdx.x;
  float2 a = st0[col], b = st1[col];
  float m = (a.x + b.x) * (1.0f/256.0f);
  float var = (a.y + b.y)*(1.0f/256.0f) - m*m;
  mu[col] = m;
  rstd[col] = rsqrtf(fmaxf(var, 0.f) + 1e-5f);
}

// ---------------- LN-apply + re-layout: h(bf16) -> U[ch][b*64+c][64] ----
__global__ __launch_bounds__(256) void k_prep(const unsigned short* __restrict__ h,
    const float* __restrict__ mu, const float* __restrict__ rstd,
    const float* __restrict__ lnw_, const float* __restrict__ lnb_,
    unsigned short* __restrict__ U, int ib){
  int idx = blockIdx.x*256 + threadIdx.x;   // B*H*L/8
  int l = (idx & 511) * 8;
  int ch = (idx >> 9) & (Hq-1);
  int b = idx >> 17;
  float lw = lnw_[ib*Hq+ch], lb = lnb_[ib*Hq+ch];
  const unsigned short* hp = h + (((size_t)(b*Hq+ch))<<12) + l;
  const float* mp = mu + ((size_t)b<<12) + l;
  const float* rp = rstd + ((size_t)b<<12) + l;
  uint4 hv = *(const uint4*)hp;
  float hf[8];
  hf[0]=bf2f(hv.x&0xffff); hf[1]=bf2f(hv.x>>16);
  hf[2]=bf2f(hv.y&0xffff); hf[3]=bf2f(hv.y>>16);
  hf[4]=bf2f(hv.z&0xffff); hf[5]=bf2f(hv.z>>16);
  hf[6]=bf2f(hv.w&0xffff); hf[7]=bf2f(hv.w>>16);
  unsigned ow[8];
  #pragma unroll
  for (int j=0;j<8;j++){
    float z = (hf[j]-mp[j])*rp[j]*lw + lb;
    ow[j] = f2bf(z);
  }
  uint4 o;
  o.x = ow[0] | (ow[1]<<16); o.y = ow[2] | (ow[3]<<16);
  o.z = ow[4] | (ow[5]<<16); o.w = ow[6] | (ow[7]<<16);
  unsigned short* up = U + ((size_t)ch*1024 + b*64 + (l>>6))*64 + (l&63);
  *(uint4*)up = o;
}

// ---------------- B-GEMM: Bb[ch][bc][n2] = Wbar[ch][n2][j] . U[ch][bc][j] ----
__global__ __launch_bounds__(256,4) void k_bgemm(const unsigned short* __restrict__ Wb,
    const unsigned short* __restrict__ U, unsigned short* __restrict__ Bb){
  __shared__ __align__(16) char smem[34816];
  unsigned short* Alds = (unsigned short*)smem;
  unsigned short* Blds = (unsigned short*)(smem+16384);
  const int tid = threadIdx.x;
  const int lam = tid & 63;
  const int wv = tid >> 6;
  const int wr = wv >> 1, wc = wv & 1;
  const int ch = blockIdx.x;
  const int bc0 = blockIdx.y * 128;
  const unsigned short* Wch = Wb + (size_t)ch*128*64;
  const unsigned short* Uch = U + (size_t)ch*1024*64;
  const int rbase = lam & 15;
  const int kg = lam >> 4;
  const int x7 = lam & 7;
  const int xo0 = ((kg) ^ x7) * 8;
  const int xo1 = ((4+kg) ^ x7) * 8;
  f32x4 acc[4][4] = {};
  #pragma unroll
  for (int c=0;c<4;c++){
    int si = c*256 + tid;
    int row = si >> 3, blk = si & 7;
    int sb = blk ^ (row & 7);
    stage16(Wch + row*64 + sb*8, &Alds[(c*256 + wv*64)*8]);
    stage16(Uch + (size_t)(bc0+row)*64 + sb*8, &Blds[(c*256 + wv*64)*8]);
  }
  __syncthreads();
  #pragma unroll
  for (int kk=0;kk<2;kk++){
    const int xo = kk ? xo1 : xo0;
    short8 af[4], wf[4];
    #pragma unroll
    for (int mf=0;mf<4;mf++)
      af[mf] = *(const short8*)&Alds[(wr*64 + mf*16 + rbase)*64 + xo];
    #pragma unroll
    for (int nf=0;nf<4;nf++)
      wf[nf] = *(const short8*)&Blds[(wc*64 + nf*16 + rbase)*64 + xo];
    #pragma unroll
    for (int mf=0;mf<4;mf++)
      #pragma unroll
      for (int nf=0;nf<4;nf++)
        acc[mf][nf] = __builtin_amdgcn_mfma_f32_16x16x32_bf16(af[mf], wf[nf], acc[mf][nf], 0,0,0);
  }
  __syncthreads();
  unsigned* tru = (unsigned*)smem;
  const int mg = lam >> 4;
  const int ncol = lam & 15;
  #pragma unroll
  for (int nf=0;nf<4;nf++){
    int bcl = wc*64 + nf*16 + ncol;
    #pragma unroll
    for (int mf=0;mf<4;mf++){
      int n2h = wr*32 + mf*8 + mg*2;
      tru[bcl*68 + n2h]     = (unsigned)f2bf(acc[mf][nf][0]) | ((unsigned)f2bf(acc[mf][nf][1])<<16);
      tru[bcl*68 + n2h + 1] = (unsigned)f2bf(acc[mf][nf][2]) | ((unsigned)f2bf(acc[mf][nf][3])<<16);
    }
  }
  __syncthreads();
  {
    int row = tid >> 1, half = tid & 1;
    const unsigned* src = tru + row*68 + half*32;
    unsigned short* dst = Bb + ((size_t)ch*1024 + bc0 + row)*128 + half*64;
    #pragma unroll
    for (int j=0;j<8;j++)
      *(uint4*)(dst + j*8) = *(const uint4*)(src + j*4);
  }
}

// ---- fused chunk-scan + Y-GEMM, one (ch,b) per block; 4-wave segmented scan ----
__global__ __launch_bounds__(256,2) void k_ygemm(const unsigned short* __restrict__ G,
    const unsigned short* __restrict__ Uz, const unsigned short* __restrict__ Bb,
    const float* __restrict__ w64re_, const float* __restrict__ w64im_,
    unsigned short* __restrict__ ybuf){
  __shared__ __align__(16) char smem[65536];
  unsigned short* Glds  = (unsigned short*)smem;            // 3*4096 shorts
  unsigned short* Blds  = (unsigned short*)(smem + 24576);  // 3*4096 shorts: z,st0,st1
  unsigned short* BbPre = (unsigned short*)(smem + 49152);  // 8192 shorts
  unsigned short* trans = BbPre;                            // reuse in epilogue
  const int tid = threadIdx.x;
  const int lam = tid & 63;
  const int wv = tid >> 6;
  const int ch = blockIdx.x;
  const int b = blockIdx.y;
  const unsigned short* Gch = G + (size_t)ch*64*192;
  const unsigned short* Uch = Uz + ((size_t)ch*1024 + b*64)*64;
  const unsigned short* Bch = Bb + ((size_t)ch*1024 + b*64)*128;
  #pragma unroll
  for (int ks=0;ks<3;ks++){
    #pragma unroll
    for (int c=0;c<2;c++){
      int si = c*256 + tid;
      int row = si >> 3, blk = si & 7;
      int sb = blk ^ (row & 7);
      stage16(Gch + row*192 + ks*64 + sb*8, &Glds[ks*4096 + (c*256 + wv*64)*8]);
    }
  }
  #pragma unroll
  for (int c=0;c<2;c++){
    int si = c*256 + tid;
    int row = si >> 3, blk = si & 7;
    int sb = blk ^ (row & 7);
    stage16(Uch + row*64 + sb*8, &Blds[(c*256 + wv*64)*8]);
  }
  #pragma unroll
  for (int c=0;c<4;c++){
    int si = c*256 + tid;
    stage16(Bch + (si>>4)*128 + (si&15)*8, &BbPre[(c*256 + wv*64)*8]);
  }
  __syncthreads();
  // ---- segmented scan: 4 waves x 16 chunks ----
  {
    const float wr64 = w64re_[ch*64 + lam];
    const float wi64 = w64im_[ch*64 + lam];
    float ar = wr64, ai = wi64;
    #pragma unroll
    for (int q=0;q<4;q++){
      float nr2 = ar*ar - ai*ai;
      float ni2 = 2.f*ar*ai;
      ar = nr2; ai = ni2;
    }
    const int c0 = wv*16;
    float sre = 0.f, sim = 0.f;
    for (int c=c0;c<c0+16;c++){
      float br = bf2f(BbPre[c*128 + lam]);
      float bi = bf2f(BbPre[c*128 + 64 + lam]);
      float t = fmaf(wr64, sre, fmaf(-wi64, sim, br));
      sim = fmaf(wr64, sim, fmaf(wi64, sre, bi));
      sre = t;
    }
    float2* segT = (float2*)&Blds[4096];
    segT[wv*64 + lam] = make_float2(sre, sim);
    __syncthreads();
    float cre = 0.f, cim = 0.f;
    for (int v=0; v<wv; v++){
      float2 T = segT[v*64 + lam];
      float nr2 = fmaf(ar, cre, fmaf(-ai, cim, T.x));
      float ni2 = fmaf(ar, cim, fmaf(ai, cre, T.y));
      cre = nr2; cim = ni2;
    }
    __syncthreads();    // all segT reads done before pass 2 overwrites the region
    sre = cre; sim = cim;
    const int pos = 2*lam;
    const int base = 4096 + (pos>>6)*4096;
    const int pp = pos & 63;
    for (int c=c0;c<c0+16;c++){
      unsigned pk = (unsigned)f2bf(sre) | ((unsigned)f2bf(sim)<<16);
      int swz = (((pp>>3) ^ (c&7))<<3) + (pp&7);
      *(unsigned*)&Blds[base + c*64 + swz] = pk;
      float br = bf2f(BbPre[c*128 + lam]);
      float bi = bf2f(BbPre[c*128 + 64 + lam]);
      float t = fmaf(wr64, sre, fmaf(-wi64, sim, br));
      sim = fmaf(wr64, sim, fmaf(wi64, sre, bi));
      sre = t;
    }
  }
  __syncthreads();
  const int rbase = lam & 15;
  const int kg = lam >> 4;
  const int x7 = lam & 7;
  f32x4 acc[4] = {};
  #pragma unroll
  for (int ks=0;ks<3;ks++){
    #pragma unroll
    for (int kk=0;kk<2;kk++){
      const int xo = ((kk*4 + kg) ^ x7) * 8;
      short8 wfr = *(const short8*)&Blds[ks*4096 + (wv*16 + rbase)*64 + xo];
      #pragma unroll
      for (int mf=0;mf<4;mf++){
        short8 afr = *(const short8*)&Glds[ks*4096 + (mf*16 + rbase)*64 + xo];
        acc[mf] = __builtin_amdgcn_mfma_f32_16x16x32_bf16(afr, wfr, acc[mf], 0,0,0);
      }
    }
  }
  const int mg = lam >> 4;
  const int ncol = lam & 15;
  const int cn = wv*16 + ncol;
  #pragma unroll
  for (int mf=0;mf<4;mf++){
    #pragma unroll
    for (int r=0;r<4;r++){
      int l = mf*16 + mg*4 + r;
      trans[cn*72 + l] = f2bf(gelu(acc[mf][r]));
    }
  }
  __syncthreads();
  {
    int cc = tid >> 2, seg = tid & 3;
    unsigned short* yp = ybuf + (((size_t)(b*Hq + ch))<<12) + cc*64 + seg*16;
    const unsigned short* src = trans + cc*72 + seg*16;
    *(uint4*)yp = *(const uint4*)src;
    *(uint4*)(yp+8) = *(const uint4*)(src+8);
  }
}

// ---------------- bf16 transpose [b][ch][l] -> [b][l][ch], 64x64 tiles --------
__global__ __launch_bounds__(256) void k_transp(const unsigned short* __restrict__ src,
    unsigned short* __restrict__ dst){
  __shared__ unsigned lds[64][65];
  const int t = threadIdx.x;
  const int tile = blockIdx.x;
  const int l0 = (tile & 63)*64;
  const int c0 = ((tile>>6)&3)*64;
  const int b = tile >> 8;
  const int rr = t >> 3, c8 = t & 7;
  #pragma unroll
  for (int q=0;q<2;q++){
    int ch = rr + q*32;
    const unsigned short* sp = src + ((size_t)b*Hq + c0+ch)*Lq + l0 + c8*8;
    uint4 v = *(const uint4*)sp;
    lds[ch][c8*8+0] = v.x & 0xffff; lds[ch][c8*8+1] = v.x >> 16;
    lds[ch][c8*8+2] = v.y & 0xffff; lds[ch][c8*8+3] = v.y >> 16;
    lds[ch][c8*8+4] = v.z & 0xffff; lds[ch][c8*8+5] = v.z >> 16;
    lds[ch][c8*8+6] = v.w & 0xffff; lds[ch][c8*8+7] = v.w >> 16;
  }
  __syncthreads();
  #pragma unroll
  for (int q=0;q<2;q++){
    int l = rr + q*32;
    unsigned a[8];
    #pragma unroll
    for (int j=0;j<8;j++) a[j] = lds[c8*8+j][l];
    uint4 o;
    o.x = (a[0]&0xffff) | (a[1]<<16);
    o.y = (a[2]&0xffff) | (a[3]<<16);
    o.z = (a[4]&0xffff) | (a[5]<<16);
    o.w = (a[6]&0xffff) | (a[7]<<16);
    *(uint4*)(dst + ((size_t)b*Lq + l0+l)*Hq + c0 + c8*8) = o;
  }
}

// ---------------- fused LN + transpose: h(bf16) -> zT[b][l][ch] ----------
__global__ __launch_bounds__(256) void k_lntransp(const unsigned short* __restrict__ h,
    const float* __restrict__ mu, const float* __restrict__ rstd,
    const float* __restrict__ lnw_, const float* __restrict__ lnb_,
    unsigned short* __restrict__ dst, int ib){
  __shared__ unsigned lds[64][65];
  const int t = threadIdx.x;
  const int tile = blockIdx.x;
  const int l0 = (tile & 63)*64;
  const int c0 = ((tile>>6)&3)*64;
  const int b = tile >> 8;
  const int rr = t >> 3, c8 = t & 7;
  #pragma unroll
  for (int q=0;q<2;q++){
    int ch = c0 + rr + q*32;
    float lw = lnw_[ib*Hq + ch], lb = lnb_[ib*Hq + ch];
    const unsigned short* sp = h + ((size_t)b*Hq + ch)*Lq + l0 + c8*8;
    const float* mp = mu + (size_t)b*Lq + l0 + c8*8;
    const float* rp = rstd + (size_t)b*Lq + l0 + c8*8;
    uint4 hv = *(const uint4*)sp;
    float hf[8];
    hf[0]=bf2f(hv.x&0xffff); hf[1]=bf2f(hv.x>>16);
    hf[2]=bf2f(hv.y&0xffff); hf[3]=bf2f(hv.y>>16);
    hf[4]=bf2f(hv.z&0xffff); hf[5]=bf2f(hv.z>>16);
    hf[6]=bf2f(hv.w&0xffff); hf[7]=bf2f(hv.w>>16);
    #pragma unroll
    for (int j=0;j<8;j++){
      float z = (hf[j] - mp[j]) * rp[j] * lw + lb;
      lds[rr + q*32][c8*8+j] = f2bf(z);
    }
  }
  __syncthreads();
  #pragma unroll
  for (int q=0;q<2;q++){
    int l = rr + q*32;
    unsigned a[8];
    #pragma unroll
    for (int j=0;j<8;j++) a[j] = lds[c8*8+j][l];
    uint4 o;
    o.x = (a[0]&0xffff) | (a[1]<<16);
    o.y = (a[2]&0xffff) | (a[3]<<16);
    o.z = (a[4]&0xffff) | (a[5]<<16);
    o.w = (a[6]&0xffff) | (a[7]<<16);
    *(uint4*)(dst + ((size_t)b*Lq + l0+l)*Hq + c0 + c8*8) = o;
  }
}

// ---- MFMA GEMM, 128x128 tile, 4 waves, single-buffer; h is bf16 ----
// MODE 0: dual-N (a,g) + GLU residual (bank-free RMW) + stats partial store
// MODE 1: bias + GELU -> bf16 out[col][512] via LDS-transposed coalesced stores
// MODE 2: bias + residual (bank-free RMW) + stats partial store
template<int MODE, int KDIM>
__global__ __launch_bounds__(256,4) void k_gemm(
    const unsigned short* __restrict__ A, const unsigned short* __restrict__ W,
    const float* __restrict__ bias, unsigned short* __restrict__ h,
    unsigned short* __restrict__ out, float2* __restrict__ stats){
  constexpr int WSH = (MODE==0?2:1)*128*64;       // W shorts
  constexpr int STG_B = (128*64 + WSH)*2;
  constexpr int EPI_B = (MODE==1) ? 128*136*2 : 64*144*4;
  constexpr int SMEM = STG_B > EPI_B ? STG_B : EPI_B;
  __shared__ __align__(16) char smem[SMEM];
  unsigned short* Alds = (unsigned short*)smem;
  unsigned short* Wlds = Alds + 128*64;
  const int tid = threadIdx.x;
  const int lam = tid & 63;
  const int wv = tid >> 6;
  const int wr = wv >> 1, wc = wv & 1;
  const int col0 = blockIdx.x * 128;
  const int n0 = blockIdx.y * 128;
  const int rbase = lam & 15;
  const int kg = lam >> 4;
  const int x7 = lam & 7;
  const int xo0 = ((kg) ^ x7) * 8;
  const int xo1 = ((4+kg) ^ x7) * 8;
  const unsigned short *aP[4], *wP[4], *wP2[4];
  unsigned sDst[4];
  #pragma unroll
  for (int c=0;c<4;c++){
    int si = c*256 + tid;
    int row = si >> 3, blk = si & 7;
    int sb = blk ^ (row & 7);
    aP[c] = A + (size_t)(col0+row)*KDIM + sb*8;
    wP[c] = W + (size_t)(n0+row)*KDIM + sb*8;
    wP2[c] = (MODE==0) ? (W + (size_t)(n0+256+row)*KDIM + sb*8) : nullptr;
    sDst[c] = (unsigned)(c*256 + wv*64)*8;
  }
  f32x4 acc[4][4] = {};
  f32x4 acc2[4][(MODE==0)?4:1] = {};
  for (int k0 = 0; k0 < KDIM; k0 += 64){
    #pragma unroll
    for (int c=0;c<4;c++){
      stage16(aP[c] + k0, &Alds[sDst[c]]);
      stage16(wP[c] + k0, &Wlds[sDst[c]]);
      if constexpr (MODE==0) stage16(wP2[c] + k0, &Wlds[8192 + sDst[c]]);
    }
    __syncthreads();
    #pragma unroll
    for (int kk=0;kk<2;kk++){
      const int xo = kk ? xo1 : xo0;
      short8 af[4], wf[4];
      #pragma unroll
      for (int mf=0;mf<4;mf++)
        af[mf] = *(const short8*)&Alds[(wr*64 + mf*16 + rbase)*64 + xo];
      #pragma unroll
      for (int nf=0;nf<4;nf++)
        wf[nf] = *(const short8*)&Wlds[(wc*64 + nf*16 + rbase)*64 + xo];
      if constexpr (MODE==0){
        short8 wg[4];
        #pragma unroll
        for (int nf=0;nf<4;nf++)
          wg[nf] = *(const short8*)&Wlds[8192 + (wc*64 + nf*16 + rbase)*64 + xo];
        #pragma unroll
        for (int mf=0;mf<4;mf++){
          #pragma unroll
          for (int nf=0;nf<4;nf++){
            acc[mf][nf]  = __builtin_amdgcn_mfma_f32_16x16x32_bf16(af[mf], wf[nf], acc[mf][nf], 0,0,0);
            acc2[mf][nf] = __builtin_amdgcn_mfma_f32_16x16x32_bf16(af[mf], wg[nf], acc2[mf][nf], 0,0,0);
          }
        }
      } else {
        #pragma unroll
        for (int mf=0;mf<4;mf++){
          #pragma unroll
          for (int nf=0;nf<4;nf++)
            acc[mf][nf] = __builtin_amdgcn_mfma_f32_16x16x32_bf16(af[mf], wf[nf], acc[mf][nf], 0,0,0);
        }
      }
    }
    __syncthreads();
  }
  const int mg = lam >> 4;
  const int ncol = lam & 15;
  if constexpr (MODE==1){
    unsigned short* trans = (unsigned short*)smem;
    #pragma unroll
    for (int nf=0;nf<4;nf++){
      int gnl = wc*64 + nf*16 + ncol;
      float bb1 = bias[n0 + gnl];
      #pragma unroll
      for (int mf=0;mf<4;mf++){
        int cl = wr*64 + mf*16 + mg*4;
        #pragma unroll
        for (int r=0;r<4;r++)
          trans[(cl+r)*136 + gnl] = f2bf(gelu(acc[mf][nf][r] + bb1));
      }
    }
    __syncthreads();
    {
      int cl = tid >> 1, gs = (tid & 1)*64;
      const unsigned short* src = trans + cl*136 + gs;
      unsigned short* dst = out + (size_t)(col0+cl)*F2q + n0 + gs;
      #pragma unroll
      for (int j=0;j<8;j++)
        *(uint4*)(dst + j*8) = *(const uint4*)(src + j*8);
    }
  } else {
    float* dlds = (float*)smem;
    const int bb = col0 >> 12;
    const int l0 = col0 & (Lq-1);
    float s0t = 0.f, s1t = 0.f;
    #pragma unroll
    for (int p=0;p<2;p++){
      __syncthreads();
      if (wc == p){
        #pragma unroll
        for (int nf=0;nf<4;nf++){
          int chl = nf*16 + ncol;
          int gn = n0 + p*64 + chl;
          float ba = bias[gn];
          float bg = (MODE==0) ? bias[gn + Hq] : 0.f;
          #pragma unroll
          for (int mf=0;mf<4;mf++){
            int coll = wr*64 + mf*16 + mg*4;
            f32x4 dv;
            #pragma unroll
            for (int r=0;r<4;r++){
              if constexpr (MODE==0){
                float av = acc[mf][nf][r] + ba;
                float gv = acc2[mf][nf][r] + bg;
                dv[r] = __fdividef(av, 1.f + __expf(-gv));
              } else {
                dv[r] = acc[mf][nf][r] + ba;
              }
            }
            *(f32x4*)&dlds[chl*144 + (coll>>5)*36 + (coll&31)] = dv;
          }
        }
      }
      __syncthreads();
      {
        int chl = tid >> 2, seg = tid & 3;
        unsigned short* hp = h + ((size_t)bb*Hq + n0 + p*64 + chl)*Lq + l0 + seg*32;
        float* dp = dlds + chl*144 + seg*36;
        #pragma unroll
        for (int j=0;j<4;j++){
          uint4 hv = *(uint4*)(hp + j*8);
          f32x4 d0 = *(const f32x4*)(dp + j*8);
          f32x4 d1 = *(const f32x4*)(dp + j*8 + 4);
          d0[0] += bf2f(hv.x&0xffff); d0[1] += bf2f(hv.x>>16);
          d0[2] += bf2f(hv.y&0xffff); d0[3] += bf2f(hv.y>>16);
          d1[0] += bf2f(hv.z&0xffff); d1[1] += bf2f(hv.z>>16);
          d1[2] += bf2f(hv.w&0xffff); d1[3] += bf2f(hv.w>>16);
          hv.x = (unsigned)f2bf(d0[0]) | ((unsigned)f2bf(d0[1])<<16);
          hv.y = (unsigned)f2bf(d0[2]) | ((unsigned)f2bf(d0[3])<<16);
          hv.z = (unsigned)f2bf(d1[0]) | ((unsigned)f2bf(d1[1])<<16);
          hv.w = (unsigned)f2bf(d1[2]) | ((unsigned)f2bf(d1[3])<<16);
          *(uint4*)(hp + j*8) = hv;
          *(f32x4*)(dp + j*8) = d0;
          *(f32x4*)(dp + j*8 + 4) = d1;
        }
      }
      __syncthreads();
      {
        int j = tid >> 1, hc = (tid & 1)*32;
        int js = (j>>5)*36 + (j&31);
        float s0 = 0.f, s1 = 0.f;
        #pragma unroll
        for (int c=0;c<32;c++){
          float v = dlds[(hc+c)*144 + js];
          s0 += v; s1 = fmaf(v, v, s1);
        }
        s0 += __shfl_xor(s0, 1, 64);
        s1 += __shfl_xor(s1, 1, 64);
        s0t += s0; s1t += s1;
      }
    }
    if (!(tid & 1)){
      float2* stP = stats + (size_t)blockIdx.y*BLq;
      stP[col0 + (tid >> 1)] = make_float2(s0t, s1t);
    }
  }
}

// ---------------- final gather ----------------
__global__ __launch_bounds__(256) void k_gather(const unsigned short* __restrict__ h,
    float* __restrict__ o){
  int idx = blockIdx.x*256 + threadIdx.x;
  int b = idx >> 8, c = idx & (Hq-1);
  o[idx] = bf2f(h[((size_t)b*Hq + c)*Lq + (Lq-1)]);
}

extern "C" void kernel_launch(void* const* d_in, const int* in_sizes, int n_in,
                              void* d_out, int out_size, void* d_ws, size_t ws_size,
                              hipStream_t stream) {
  (void)in_sizes; (void)n_in; (void)out_size; (void)ws_size;
  const float* x         = (const float*)d_in[0];
  const float* conv_w    = (const float*)d_in[1];
  const float* conv_b    = (const float*)d_in[2];
  const float* s4_norm_w = (const float*)d_in[3];
  const float* s4_norm_b = (const float*)d_in[4];
  const float* log_dt    = (const float*)d_in[5];
  const float* log_A_real= (const float*)d_in[6];
  const float* A_imag    = (const float*)d_in[7];
  const float* C_re      = (const float*)d_in[8];
  const float* C_im      = (const float*)d_in[9];
  const float* Dp        = (const float*)d_in[10];
  const float* s4_out_w  = (const float*)d_in[11];
  const float* s4_out_b  = (const float*)d_in[12];
  const float* ff_norm_w = (const float*)d_in[13];
  const float* ff_norm_b = (const float*)d_in[14];
  const float* ff_w1     = (const float*)d_in[15];
  const float* ff_b1     = (const float*)d_in[16];
  const float* ff_w2     = (const float*)d_in[17];
  const float* ff_b2     = (const float*)d_in[18];

  char* ws = (char*)d_ws;
  size_t off = 0;
  auto nxt = [&](size_t bytes){ size_t o = off; off = (off + bytes + 255) & ~(size_t)255; return o; };
  unsigned short* h = (unsigned short*)(ws + nxt((size_t)Bq*Hq*Lq*2));   // 32MB bf16
  float* mu     = (float*)(ws + nxt((size_t)BLq*4));
  float* rstd   = (float*)(ws + nxt((size_t)BLq*4));
  float* wre    = (float*)(ws + nxt((size_t)NBq*Hq*Nq*4));
  float* wim    = (float*)(ws + nxt((size_t)NBq*Hq*Nq*4));
  float* c2re   = (float*)(ws + nxt((size_t)NBq*Hq*Nq*4));
  float* c2im   = (float*)(ws + nxt((size_t)NBq*Hq*Nq*4));
  float* w64re  = (float*)(ws + nxt((size_t)NBq*Hq*Nq*4));
  float* w64im  = (float*)(ws + nxt((size_t)NBq*Hq*Nq*4));
  unsigned short* s4wb = (unsigned short*)(ws + nxt((size_t)NBq*F2q*Hq*2));
  unsigned short* f1b  = (unsigned short*)(ws + nxt((size_t)NBq*F2q*Hq*2));
  unsigned short* f2b  = (unsigned short*)(ws + nxt((size_t)NBq*Hq*F2q*2));
  unsigned short* Gm   = (unsigned short*)(ws + nxt((size_t)NBq*Hq*64*192*2)); // 24MB (x4)
  unsigned short* Wbar = (unsigned short*)(ws + nxt((size_t)NBq*Hq*128*64*2)); // 16MB (x4)
  unsigned short* U    = (unsigned short*)(ws + nxt((size_t)Hq*1024*64*2));    // 32MB (z only)
  unsigned short* Bb   = (unsigned short*)(ws + nxt((size_t)Hq*128*1024*2));   // 64MB
  unsigned short* ZBUF = (unsigned short*)(ws + nxt((size_t)BLq*F2q*2));       // 64MB
  // aliases (lifetime-checked):
  unsigned short* yT   = ZBUF;                               // transp -> gemm0
  unsigned short* ybuf = ZBUF + (size_t)16*1024*1024;        // ygemm -> transp
  unsigned short* z2T  = ZBUF;                               // gemm1 -> gemm2
  unsigned short* zT   = Bb + (size_t)16*1024*1024;          // lntransp -> gemm1 (Bb dead)
  float2* st0 = (float2*)Bb;                                 // gemm epi -> lnfin
  float2* st1 = st0 + BLq;

  k_convln<<<Bq*16, 256, 0, stream>>>(x, conv_w, conv_b, h, mu, rstd);
  k_s4pre<<<(NBq*Hq*Nq)/256, 256, 0, stream>>>(log_dt, log_A_real, A_imag, C_re, C_im,
                                               wre, wim, c2re, c2im);
  k_cvtw<<<(NBq*F2q*Hq)/256, 256, 0, stream>>>(s4_out_w, ff_w1, ff_w2, s4wb, f1b, f2b);
  k_s4mat<<<NBq*Hq, 64, 0, stream>>>(wre, wim, c2re, c2im, Dp, Gm, Wbar, w64re, w64im);

  for (int i=0;i<NBq;i++){
    const size_t po = (size_t)i*Hq*Nq;
    const unsigned short* Gmi   = Gm   + (size_t)i*Hq*64*192;
    const unsigned short* Wbari = Wbar + (size_t)i*Hq*128*64;
    // ---- S4 residual block ----
    k_prep<<<(Bq*Hq*Lq/8)/256, 256, 0, stream>>>(h, mu, rstd, s4_norm_w, s4_norm_b, U, i);
    k_bgemm<<<dim3(Hq, 8), 256, 0, stream>>>(Wbari, U, Bb);
    k_ygemm<<<dim3(Hq, Bq), 256, 0, stream>>>(Gmi, U, Bb, w64re+po, w64im+po, ybuf);
    k_transp<<<Bq*4*64, 256, 0, stream>>>(ybuf, yT);
    k_gemm<0,256><<<dim3(BLq/128, 2), 256, 0, stream>>>(
        yT, s4wb + (size_t)i*F2q*Hq, s4_out_b + (size_t)i*F2q, h, nullptr, st0);
    k_lnfin<<<BLq/256, 256, 0, stream>>>(st0, st1, mu, rstd);
    // ---- FF residual block ----
    k_lntransp<<<Bq*4*64, 256, 0, stream>>>(h, mu, rstd, ff_norm_w, ff_norm_b, zT, i);
    k_gemm<1,256><<<dim3(BLq/128, 4), 256, 0, stream>>>(
        zT, f1b + (size_t)i*F2q*Hq, ff_b1 + (size_t)i*F2q, nullptr, z2T, nullptr);
    k_gemm<2,512><<<dim3(BLq/128, 2), 256, 0, stream>>>(
        z2T, f2b + (size_t)i*Hq*F2q, ff_b2 + (size_t)i*Hq, h, nullptr, st0);
    if (i < NBq-1)
      k_lnfin<<<BLq/256, 256, 0, stream>>>(st0, st1, mu, rstd);
  }
  k_gather<<<(Bq*Hq)/256, 256, 0, stream>>>(h, (float*)d_out);
}

// Round 18
// 1101.518 us; speedup vs baseline: 1.0783x; 1.0783x over previous
//
#include <hip/hip_runtime.h>
#include <math.h>

#define Bq 16
#define Lq 4096
#define Hq 256
#define Nq 64
#define NBq 4
#define F2q 512
#define BLq (Bq*Lq)

typedef __attribute__((ext_vector_type(8))) short short8;
typedef __attribute__((ext_vector_type(4))) float f32x4;

__device__ __forceinline__ unsigned short f2bf(float f){
  unsigned u = __float_as_uint(f);
  u = (u + 0x7fffu + ((u >> 16) & 1u)) >> 16;
  return (unsigned short)u;
}
__device__ __forceinline__ float bf2f(unsigned short u){
  return __uint_as_float(((unsigned)u) << 16);
}
// tanh-approx GELU (max abs err ~3e-4, well under bf16 rounding)
__device__ __forceinline__ float gelu(float x){
  float u = 0.79788456f*x*(1.f + 0.044715f*x*x);
  float t = 1.f - __fdividef(2.f, 1.f + __expf(2.f*fabsf(u)));
  return 0.5f*x*(1.f + copysignf(t, u));
}

__device__ __forceinline__ void stage16(const void* g, void* l){
  __builtin_amdgcn_global_load_lds((const __attribute__((address_space(1))) void*)g,
                                   (__attribute__((address_space(3))) void*)l, 16, 0, 0);
}

// ---------------- conv stem + fused LN stats: h[b][c][l] (bf16), mu, rstd ----
__global__ __launch_bounds__(256) void k_convln(const float* __restrict__ x,
    const float* __restrict__ cw, const float* __restrict__ cb,
    unsigned short* __restrict__ h, float* __restrict__ mu, float* __restrict__ rstd){
  __shared__ float xs[260];
  __shared__ float cwS[Hq*5];
  __shared__ float cbS[Hq];
  const int b = blockIdx.x >> 4;
  const int l0 = (blockIdx.x & 15) * 256;
  const int tid = threadIdx.x;
  for (int i=tid; i<Hq*5; i+=256) cwS[i] = cw[i];
  cbS[tid] = cb[tid];
  {
    int gl = l0 + tid - 2;
    xs[tid] = (gl>=0 && gl<Lq) ? x[(size_t)b*Lq + gl] : 0.f;
    if (tid < 4){
      int gl2 = l0 + 254 + tid;
      xs[256+tid] = (gl2>=0 && gl2<Lq) ? x[(size_t)b*Lq + gl2] : 0.f;
    }
  }
  __syncthreads();
  float s0=0.f, s1=0.f;
  unsigned short* hp = h + (size_t)b*Hq*Lq + l0 + tid;
  for (int c=0;c<Hq;c++){
    float acc = cbS[c];
    #pragma unroll
    for (int k=0;k<5;k++) acc = fmaf(cwS[c*5+k], xs[tid+k], acc);
    hp[(size_t)c*Lq] = f2bf(acc);
    s0 += acc; s1 = fmaf(acc, acc, s1);
  }
  int col = b*Lq + l0 + tid;
  float m = s0 * (1.0f/256.0f);
  float var = s1*(1.0f/256.0f) - m*m;
  mu[col] = m;
  rstd[col] = rsqrtf(fmaxf(var, 0.f) + 1e-5f);
}

// ---------------- S4D param precompute ----------------
__global__ __launch_bounds__(256) void k_s4pre(const float* __restrict__ log_dt,
    const float* __restrict__ lar, const float* __restrict__ aim,
    const float* __restrict__ cre, const float* __restrict__ cim,
    float* __restrict__ wre, float* __restrict__ wim,
    float* __restrict__ c2re, float* __restrict__ c2im){
  int idx = blockIdx.x*256 + threadIdx.x;           // NB*H*N
  int hh = (idx >> 6) & (Hq-1);
  int i = idx >> 14;
  float dt = expf(log_dt[i*Hq + hh]);
  float are = -expf(lar[idx]);
  float ai  = aim[idx];
  float dre = are*dt, dim = ai*dt;
  float er = expf(dre);
  float wr = er*cosf(dim), wi = er*sinf(dim);
  float nr = wr - 1.f, ni = wi;
  float den = are*are + ai*ai;
  float qre = (nr*are + ni*ai)/den;
  float qim = (ni*are - nr*ai)/den;
  float Cr = cre[idx], Ci = cim[idx];
  float cer = Cr*qre - Ci*qim;
  float cei = Cr*qim + Ci*qre;
  wre[idx] = wr; wim[idx] = wi;
  c2re[idx] = 2.f*cer; c2im[idx] = 2.f*cei;
}

// ---------------- weights -> bf16 ----------------
__global__ __launch_bounds__(256) void k_cvtw(const float* __restrict__ s0,
    const float* __restrict__ s1, const float* __restrict__ s2,
    unsigned short* __restrict__ d0, unsigned short* __restrict__ d1,
    unsigned short* __restrict__ d2){
  int idx = blockIdx.x*256 + threadIdx.x;
  d0[idx] = f2bf(s0[idx]);
  d1[idx] = f2bf(s1[idx]);
  d2[idx] = f2bf(s2[idx]);
}

// ---- per-(block,ch) matrices (ALL blocks): G=[T | interleave(Ere,-Eim)], Wbar, w64 ----
__global__ __launch_bounds__(64) void k_s4mat(const float* __restrict__ wre_,
    const float* __restrict__ wim_, const float* __restrict__ c2re_,
    const float* __restrict__ c2im_, const float* __restrict__ Dp,
    unsigned short* __restrict__ G, unsigned short* __restrict__ Wb,
    float* __restrict__ w64re_, float* __restrict__ w64im_){
  __shared__ float Kv[64];
  const int n = threadIdx.x;
  const int bcid = blockIdx.x;              // ib*256 + ch, 0..NB*H-1
  const int pidx = bcid*64 + n;
  const float wr = wre_[pidx], wi = wim_[pidx];
  const float cr = c2re_[pidx], ci = c2im_[pidx];
  unsigned short* Gb = G + (size_t)bcid*64*192;
  unsigned short* Wbb = Wb + (size_t)bcid*128*64;
  float pre = 1.f, pim = 0.f;
  for (int t=0;t<64;t++){
    float a = cr*pre - ci*pim;
    #pragma unroll
    for (int m=1;m<64;m<<=1) a += __shfl_xor(a, m, 64);
    if (n==0) Kv[t] = a;
    Wbb[n*64 + (63-t)] = f2bf(pre);
    Wbb[(64+n)*64 + (63-t)] = f2bf(pim);
    float qre = pre*wr - pim*wi;
    float qim = pre*wi + pim*wr;
    unsigned pk = (unsigned)f2bf(cr*qre - ci*qim)
                | ((unsigned)f2bf(-(cr*qim + ci*qre)) << 16);
    *(unsigned*)&Gb[t*192 + 64 + 2*n] = pk;   // interleaved (Ere, -Eim)
    pre = qre; pim = qim;
  }
  w64re_[pidx] = pre; w64im_[pidx] = pim;
  __syncthreads();
  float dv = Dp[bcid];
  for (int t=0;t<64;t++){
    float kv = (n<=t) ? Kv[t-n] : 0.f;
    if (n==t) kv += dv;
    Gb[t*192 + n] = f2bf(kv);
  }
}

// ---------------- finalize LN stats from two partial buffers ----------------
__global__ __launch_bounds__(256) void k_lnfin(const float2* __restrict__ st0,
    const float2* __restrict__ st1, float* __restrict__ mu, float* __restrict__ rstd){
  int col = blockIdx.x*256 + threadIdx.x;
  float2 a = st0[col], b = st1[col];
  float m = (a.x + b.x) * (1.0f/256.0f);
  float var = (a.y + b.y)*(1.0f/256.0f) - m*m;
  mu[col] = m;
  rstd[col] = rsqrtf(fmaxf(var, 0.f) + 1e-5f);
}

// ---------------- LN-apply + re-layout: h(bf16) -> U[ch][b*64+c][64] ----
__global__ __launch_bounds__(256) void k_prep(const unsigned short* __restrict__ h,
    const float* __restrict__ mu, const float* __restrict__ rstd,
    const float* __restrict__ lnw_, const float* __restrict__ lnb_,
    unsigned short* __restrict__ U, int ib){
  int idx = blockIdx.x*256 + threadIdx.x;   // B*H*L/8
  int l = (idx & 511) * 8;
  int ch = (idx >> 9) & (Hq-1);
  int b = idx >> 17;
  float lw = lnw_[ib*Hq+ch], lb = lnb_[ib*Hq+ch];
  const unsigned short* hp = h + (((size_t)(b*Hq+ch))<<12) + l;
  const float* mp = mu + ((size_t)b<<12) + l;
  const float* rp = rstd + ((size_t)b<<12) + l;
  uint4 hv = *(const uint4*)hp;
  float hf[8];
  hf[0]=bf2f(hv.x&0xffff); hf[1]=bf2f(hv.x>>16);
  hf[2]=bf2f(hv.y&0xffff); hf[3]=bf2f(hv.y>>16);
  hf[4]=bf2f(hv.z&0xffff); hf[5]=bf2f(hv.z>>16);
  hf[6]=bf2f(hv.w&0xffff); hf[7]=bf2f(hv.w>>16);
  unsigned ow[8];
  #pragma unroll
  for (int j=0;j<8;j++){
    float z = (hf[j]-mp[j])*rp[j]*lw + lb;
    ow[j] = f2bf(z);
  }
  uint4 o;
  o.x = ow[0] | (ow[1]<<16); o.y = ow[2] | (ow[3]<<16);
  o.z = ow[4] | (ow[5]<<16); o.w = ow[6] | (ow[7]<<16);
  unsigned short* up = U + ((size_t)ch*1024 + b*64 + (l>>6))*64 + (l&63);
  *(uint4*)up = o;
}

// ---------------- B-GEMM: Bb[ch][bc][n2] = Wbar[ch][n2][j] . U[ch][bc][j] ----
__global__ __launch_bounds__(256,2) void k_bgemm(const unsigned short* __restrict__ Wb,
    const unsigned short* __restrict__ U, unsigned short* __restrict__ Bb){
  __shared__ __align__(16) char smem[34816];
  unsigned short* Alds = (unsigned short*)smem;
  unsigned short* Blds = (unsigned short*)(smem+16384);
  const int tid = threadIdx.x;
  const int lam = tid & 63;
  const int wv = tid >> 6;
  const int wr = wv >> 1, wc = wv & 1;
  const int ch = blockIdx.x;
  const int bc0 = blockIdx.y * 128;
  const unsigned short* Wch = Wb + (size_t)ch*128*64;
  const unsigned short* Uch = U + (size_t)ch*1024*64;
  const int rbase = lam & 15;
  const int kg = lam >> 4;
  const int x7 = lam & 7;
  const int xo0 = ((kg) ^ x7) * 8;
  const int xo1 = ((4+kg) ^ x7) * 8;
  f32x4 acc[4][4] = {};
  #pragma unroll
  for (int c=0;c<4;c++){
    int si = c*256 + tid;
    int row = si >> 3, blk = si & 7;
    int sb = blk ^ (row & 7);
    stage16(Wch + row*64 + sb*8, &Alds[(c*256 + wv*64)*8]);
    stage16(Uch + (size_t)(bc0+row)*64 + sb*8, &Blds[(c*256 + wv*64)*8]);
  }
  __syncthreads();
  #pragma unroll
  for (int kk=0;kk<2;kk++){
    const int xo = kk ? xo1 : xo0;
    short8 af[4], wf[4];
    #pragma unroll
    for (int mf=0;mf<4;mf++)
      af[mf] = *(const short8*)&Alds[(wr*64 + mf*16 + rbase)*64 + xo];
    #pragma unroll
    for (int nf=0;nf<4;nf++)
      wf[nf] = *(const short8*)&Blds[(wc*64 + nf*16 + rbase)*64 + xo];
    #pragma unroll
    for (int mf=0;mf<4;mf++)
      #pragma unroll
      for (int nf=0;nf<4;nf++)
        acc[mf][nf] = __builtin_amdgcn_mfma_f32_16x16x32_bf16(af[mf], wf[nf], acc[mf][nf], 0,0,0);
  }
  __syncthreads();
  unsigned* tru = (unsigned*)smem;
  const int mg = lam >> 4;
  const int ncol = lam & 15;
  #pragma unroll
  for (int nf=0;nf<4;nf++){
    int bcl = wc*64 + nf*16 + ncol;
    #pragma unroll
    for (int mf=0;mf<4;mf++){
      int n2h = wr*32 + mf*8 + mg*2;
      tru[bcl*68 + n2h]     = (unsigned)f2bf(acc[mf][nf][0]) | ((unsigned)f2bf(acc[mf][nf][1])<<16);
      tru[bcl*68 + n2h + 1] = (unsigned)f2bf(acc[mf][nf][2]) | ((unsigned)f2bf(acc[mf][nf][3])<<16);
    }
  }
  __syncthreads();
  {
    int row = tid >> 1, half = tid & 1;
    const unsigned* src = tru + row*68 + half*32;
    unsigned short* dst = Bb + ((size_t)ch*1024 + bc0 + row)*128 + half*64;
    #pragma unroll
    for (int j=0;j<8;j++)
      *(uint4*)(dst + j*8) = *(const uint4*)(src + j*4);
  }
}

// ---- fused chunk-scan + Y-GEMM, one (ch,b) per block; 4-wave segmented scan ----
__global__ __launch_bounds__(256,2) void k_ygemm(const unsigned short* __restrict__ G,
    const unsigned short* __restrict__ Uz, const unsigned short* __restrict__ Bb,
    const float* __restrict__ w64re_, const float* __restrict__ w64im_,
    unsigned short* __restrict__ ybuf){
  __shared__ __align__(16) char smem[65536];
  unsigned short* Glds  = (unsigned short*)smem;            // 3*4096 shorts
  unsigned short* Blds  = (unsigned short*)(smem + 24576);  // 3*4096 shorts: z,st0,st1
  unsigned short* BbPre = (unsigned short*)(smem + 49152);  // 8192 shorts
  unsigned short* trans = BbPre;                            // reuse in epilogue
  const int tid = threadIdx.x;
  const int lam = tid & 63;
  const int wv = tid >> 6;
  const int ch = blockIdx.x;
  const int b = blockIdx.y;
  const unsigned short* Gch = G + (size_t)ch*64*192;
  const unsigned short* Uch = Uz + ((size_t)ch*1024 + b*64)*64;
  const unsigned short* Bch = Bb + ((size_t)ch*1024 + b*64)*128;
  #pragma unroll
  for (int ks=0;ks<3;ks++){
    #pragma unroll
    for (int c=0;c<2;c++){
      int si = c*256 + tid;
      int row = si >> 3, blk = si & 7;
      int sb = blk ^ (row & 7);
      stage16(Gch + row*192 + ks*64 + sb*8, &Glds[ks*4096 + (c*256 + wv*64)*8]);
    }
  }
  #pragma unroll
  for (int c=0;c<2;c++){
    int si = c*256 + tid;
    int row = si >> 3, blk = si & 7;
    int sb = blk ^ (row & 7);
    stage16(Uch + row*64 + sb*8, &Blds[(c*256 + wv*64)*8]);
  }
  #pragma unroll
  for (int c=0;c<4;c++){
    int si = c*256 + tid;
    stage16(Bch + (si>>4)*128 + (si&15)*8, &BbPre[(c*256 + wv*64)*8]);
  }
  __syncthreads();
  // ---- segmented scan: 4 waves x 16 chunks ----
  {
    const float wr64 = w64re_[ch*64 + lam];
    const float wi64 = w64im_[ch*64 + lam];
    float ar = wr64, ai = wi64;
    #pragma unroll
    for (int q=0;q<4;q++){
      float nr2 = ar*ar - ai*ai;
      float ni2 = 2.f*ar*ai;
      ar = nr2; ai = ni2;
    }
    const int c0 = wv*16;
    float sre = 0.f, sim = 0.f;
    for (int c=c0;c<c0+16;c++){
      float br = bf2f(BbPre[c*128 + lam]);
      float bi = bf2f(BbPre[c*128 + 64 + lam]);
      float t = fmaf(wr64, sre, fmaf(-wi64, sim, br));
      sim = fmaf(wr64, sim, fmaf(wi64, sre, bi));
      sre = t;
    }
    float2* segT = (float2*)&Blds[4096];
    segT[wv*64 + lam] = make_float2(sre, sim);
    __syncthreads();
    float cre = 0.f, cim = 0.f;
    for (int v=0; v<wv; v++){
      float2 T = segT[v*64 + lam];
      float nr2 = fmaf(ar, cre, fmaf(-ai, cim, T.x));
      float ni2 = fmaf(ar, cim, fmaf(ai, cre, T.y));
      cre = nr2; cim = ni2;
    }
    __syncthreads();    // all segT reads done before pass 2 overwrites the region
    sre = cre; sim = cim;
    const int pos = 2*lam;
    const int base = 4096 + (pos>>6)*4096;
    const int pp = pos & 63;
    for (int c=c0;c<c0+16;c++){
      unsigned pk = (unsigned)f2bf(sre) | ((unsigned)f2bf(sim)<<16);
      int swz = (((pp>>3) ^ (c&7))<<3) + (pp&7);
      *(unsigned*)&Blds[base + c*64 + swz] = pk;
      float br = bf2f(BbPre[c*128 + lam]);
      float bi = bf2f(BbPre[c*128 + 64 + lam]);
      float t = fmaf(wr64, sre, fmaf(-wi64, sim, br));
      sim = fmaf(wr64, sim, fmaf(wi64, sre, bi));
      sre = t;
    }
  }
  __syncthreads();
  const int rbase = lam & 15;
  const int kg = lam >> 4;
  const int x7 = lam & 7;
  f32x4 acc[4] = {};
  #pragma unroll
  for (int ks=0;ks<3;ks++){
    #pragma unroll
    for (int kk=0;kk<2;kk++){
      const int xo = ((kk*4 + kg) ^ x7) * 8;
      short8 wfr = *(const short8*)&Blds[ks*4096 + (wv*16 + rbase)*64 + xo];
      #pragma unroll
      for (int mf=0;mf<4;mf++){
        short8 afr = *(const short8*)&Glds[ks*4096 + (mf*16 + rbase)*64 + xo];
        acc[mf] = __builtin_amdgcn_mfma_f32_16x16x32_bf16(afr, wfr, acc[mf], 0,0,0);
      }
    }
  }
  const int mg = lam >> 4;
  const int ncol = lam & 15;
  const int cn = wv*16 + ncol;
  #pragma unroll
  for (int mf=0;mf<4;mf++){
    #pragma unroll
    for (int r=0;r<4;r++){
      int l = mf*16 + mg*4 + r;
      trans[cn*72 + l] = f2bf(gelu(acc[mf][r]));
    }
  }
  __syncthreads();
  {
    int cc = tid >> 2, seg = tid & 3;
    unsigned short* yp = ybuf + (((size_t)(b*Hq + ch))<<12) + cc*64 + seg*16;
    const unsigned short* src = trans + cc*72 + seg*16;
    *(uint4*)yp = *(const uint4*)src;
    *(uint4*)(yp+8) = *(const uint4*)(src+8);
  }
}

// ---------------- bf16 transpose [b][ch][l] -> [b][l][ch], 64x64 tiles --------
__global__ __launch_bounds__(256) void k_transp(const unsigned short* __restrict__ src,
    unsigned short* __restrict__ dst){
  __shared__ unsigned lds[64][65];
  const int t = threadIdx.x;
  const int tile = blockIdx.x;
  const int l0 = (tile & 63)*64;
  const int c0 = ((tile>>6)&3)*64;
  const int b = tile >> 8;
  const int rr = t >> 3, c8 = t & 7;
  #pragma unroll
  for (int q=0;q<2;q++){
    int ch = rr + q*32;
    const unsigned short* sp = src + ((size_t)b*Hq + c0+ch)*Lq + l0 + c8*8;
    uint4 v = *(const uint4*)sp;
    lds[ch][c8*8+0] = v.x & 0xffff; lds[ch][c8*8+1] = v.x >> 16;
    lds[ch][c8*8+2] = v.y & 0xffff; lds[ch][c8*8+3] = v.y >> 16;
    lds[ch][c8*8+4] = v.z & 0xffff; lds[ch][c8*8+5] = v.z >> 16;
    lds[ch][c8*8+6] = v.w & 0xffff; lds[ch][c8*8+7] = v.w >> 16;
  }
  __syncthreads();
  #pragma unroll
  for (int q=0;q<2;q++){
    int l = rr + q*32;
    unsigned a[8];
    #pragma unroll
    for (int j=0;j<8;j++) a[j] = lds[c8*8+j][l];
    uint4 o;
    o.x = (a[0]&0xffff) | (a[1]<<16);
    o.y = (a[2]&0xffff) | (a[3]<<16);
    o.z = (a[4]&0xffff) | (a[5]<<16);
    o.w = (a[6]&0xffff) | (a[7]<<16);
    *(uint4*)(dst + ((size_t)b*Lq + l0+l)*Hq + c0 + c8*8) = o;
  }
}

// ---------------- fused LN + transpose: h(bf16) -> zT[b][l][ch] ----------
__global__ __launch_bounds__(256) void k_lntransp(const unsigned short* __restrict__ h,
    const float* __restrict__ mu, const float* __restrict__ rstd,
    const float* __restrict__ lnw_, const float* __restrict__ lnb_,
    unsigned short* __restrict__ dst, int ib){
  __shared__ unsigned lds[64][65];
  const int t = threadIdx.x;
  const int tile = blockIdx.x;
  const int l0 = (tile & 63)*64;
  const int c0 = ((tile>>6)&3)*64;
  const int b = tile >> 8;
  const int rr = t >> 3, c8 = t & 7;
  #pragma unroll
  for (int q=0;q<2;q++){
    int ch = c0 + rr + q*32;
    float lw = lnw_[ib*Hq + ch], lb = lnb_[ib*Hq + ch];
    const unsigned short* sp = h + ((size_t)b*Hq + ch)*Lq + l0 + c8*8;
    const float* mp = mu + (size_t)b*Lq + l0 + c8*8;
    const float* rp = rstd + (size_t)b*Lq + l0 + c8*8;
    uint4 hv = *(const uint4*)sp;
    float hf[8];
    hf[0]=bf2f(hv.x&0xffff); hf[1]=bf2f(hv.x>>16);
    hf[2]=bf2f(hv.y&0xffff); hf[3]=bf2f(hv.y>>16);
    hf[4]=bf2f(hv.z&0xffff); hf[5]=bf2f(hv.z>>16);
    hf[6]=bf2f(hv.w&0xffff); hf[7]=bf2f(hv.w>>16);
    #pragma unroll
    for (int j=0;j<8;j++){
      float z = (hf[j] - mp[j]) * rp[j] * lw + lb;
      lds[rr + q*32][c8*8+j] = f2bf(z);
    }
  }
  __syncthreads();
  #pragma unroll
  for (int q=0;q<2;q++){
    int l = rr + q*32;
    unsigned a[8];
    #pragma unroll
    for (int j=0;j<8;j++) a[j] = lds[c8*8+j][l];
    uint4 o;
    o.x = (a[0]&0xffff) | (a[1]<<16);
    o.y = (a[2]&0xffff) | (a[3]<<16);
    o.z = (a[4]&0xffff) | (a[5]<<16);
    o.w = (a[6]&0xffff) | (a[7]<<16);
    *(uint4*)(dst + ((size_t)b*Lq + l0+l)*Hq + c0 + c8*8) = o;
  }
}

// ---- MFMA GEMM, 128x128 tile, 4 waves, single-buffer; h is bf16 ----
// MODE 0: dual-N (a,g) + GLU residual (bank-free RMW) + stats partial store
// MODE 1: bias + GELU -> bf16 out[col][512] via LDS-transposed coalesced stores
// MODE 2: bias + residual (bank-free RMW) + stats partial store
template<int MODE, int KDIM>
__global__ __launch_bounds__(256,2) void k_gemm(
    const unsigned short* __restrict__ A, const unsigned short* __restrict__ W,
    const float* __restrict__ bias, unsigned short* __restrict__ h,
    unsigned short* __restrict__ out, float2* __restrict__ stats){
  constexpr int WSH = (MODE==0?2:1)*128*64;       // W shorts
  constexpr int STG_B = (128*64 + WSH)*2;
  constexpr int EPI_B = (MODE==1) ? 128*136*2 : 64*144*4;
  constexpr int SMEM = STG_B > EPI_B ? STG_B : EPI_B;
  __shared__ __align__(16) char smem[SMEM];
  unsigned short* Alds = (unsigned short*)smem;
  unsigned short* Wlds = Alds + 128*64;
  const int tid = threadIdx.x;
  const int lam = tid & 63;
  const int wv = tid >> 6;
  const int wr = wv >> 1, wc = wv & 1;
  const int col0 = blockIdx.x * 128;
  const int n0 = blockIdx.y * 128;
  const int rbase = lam & 15;
  const int kg = lam >> 4;
  const int x7 = lam & 7;
  const int xo0 = ((kg) ^ x7) * 8;
  const int xo1 = ((4+kg) ^ x7) * 8;
  const unsigned short *aP[4], *wP[4], *wP2[4];
  unsigned sDst[4];
  #pragma unroll
  for (int c=0;c<4;c++){
    int si = c*256 + tid;
    int row = si >> 3, blk = si & 7;
    int sb = blk ^ (row & 7);
    aP[c] = A + (size_t)(col0+row)*KDIM + sb*8;
    wP[c] = W + (size_t)(n0+row)*KDIM + sb*8;
    wP2[c] = (MODE==0) ? (W + (size_t)(n0+256+row)*KDIM + sb*8) : nullptr;
    sDst[c] = (unsigned)(c*256 + wv*64)*8;
  }
  f32x4 acc[4][4] = {};
  f32x4 acc2[4][(MODE==0)?4:1] = {};
  for (int k0 = 0; k0 < KDIM; k0 += 64){
    #pragma unroll
    for (int c=0;c<4;c++){
      stage16(aP[c] + k0, &Alds[sDst[c]]);
      stage16(wP[c] + k0, &Wlds[sDst[c]]);
      if constexpr (MODE==0) stage16(wP2[c] + k0, &Wlds[8192 + sDst[c]]);
    }
    __syncthreads();
    #pragma unroll
    for (int kk=0;kk<2;kk++){
      const int xo = kk ? xo1 : xo0;
      short8 af[4], wf[4];
      #pragma unroll
      for (int mf=0;mf<4;mf++)
        af[mf] = *(const short8*)&Alds[(wr*64 + mf*16 + rbase)*64 + xo];
      #pragma unroll
      for (int nf=0;nf<4;nf++)
        wf[nf] = *(const short8*)&Wlds[(wc*64 + nf*16 + rbase)*64 + xo];
      if constexpr (MODE==0){
        short8 wg[4];
        #pragma unroll
        for (int nf=0;nf<4;nf++)
          wg[nf] = *(const short8*)&Wlds[8192 + (wc*64 + nf*16 + rbase)*64 + xo];
        #pragma unroll
        for (int mf=0;mf<4;mf++){
          #pragma unroll
          for (int nf=0;nf<4;nf++){
            acc[mf][nf]  = __builtin_amdgcn_mfma_f32_16x16x32_bf16(af[mf], wf[nf], acc[mf][nf], 0,0,0);
            acc2[mf][nf] = __builtin_amdgcn_mfma_f32_16x16x32_bf16(af[mf], wg[nf], acc2[mf][nf], 0,0,0);
          }
        }
      } else {
        #pragma unroll
        for (int mf=0;mf<4;mf++){
          #pragma unroll
          for (int nf=0;nf<4;nf++)
            acc[mf][nf] = __builtin_amdgcn_mfma_f32_16x16x32_bf16(af[mf], wf[nf], acc[mf][nf], 0,0,0);
        }
      }
    }
    __syncthreads();
  }
  const int mg = lam >> 4;
  const int ncol = lam & 15;
  if constexpr (MODE==1){
    unsigned short* trans = (unsigned short*)smem;
    #pragma unroll
    for (int nf=0;nf<4;nf++){
      int gnl = wc*64 + nf*16 + ncol;
      float bb1 = bias[n0 + gnl];
      #pragma unroll
      for (int mf=0;mf<4;mf++){
        int cl = wr*64 + mf*16 + mg*4;
        #pragma unroll
        for (int r=0;r<4;r++)
          trans[(cl+r)*136 + gnl] = f2bf(gelu(acc[mf][nf][r] + bb1));
      }
    }
    __syncthreads();
    {
      int cl = tid >> 1, gs = (tid & 1)*64;
      const unsigned short* src = trans + cl*136 + gs;
      unsigned short* dst = out + (size_t)(col0+cl)*F2q + n0 + gs;
      #pragma unroll
      for (int j=0;j<8;j++)
        *(uint4*)(dst + j*8) = *(const uint4*)(src + j*8);
    }
  } else {
    float* dlds = (float*)smem;
    const int bb = col0 >> 12;
    const int l0 = col0 & (Lq-1);
    float s0t = 0.f, s1t = 0.f;
    #pragma unroll
    for (int p=0;p<2;p++){
      __syncthreads();
      if (wc == p){
        #pragma unroll
        for (int nf=0;nf<4;nf++){
          int chl = nf*16 + ncol;
          int gn = n0 + p*64 + chl;
          float ba = bias[gn];
          float bg = (MODE==0) ? bias[gn + Hq] : 0.f;
          #pragma unroll
          for (int mf=0;mf<4;mf++){
            int coll = wr*64 + mf*16 + mg*4;
            f32x4 dv;
            #pragma unroll
            for (int r=0;r<4;r++){
              if constexpr (MODE==0){
                float av = acc[mf][nf][r] + ba;
                float gv = acc2[mf][nf][r] + bg;
                dv[r] = __fdividef(av, 1.f + __expf(-gv));
              } else {
                dv[r] = acc[mf][nf][r] + ba;
              }
            }
            *(f32x4*)&dlds[chl*144 + (coll>>5)*36 + (coll&31)] = dv;
          }
        }
      }
      __syncthreads();
      {
        int chl = tid >> 2, seg = tid & 3;
        unsigned short* hp = h + ((size_t)bb*Hq + n0 + p*64 + chl)*Lq + l0 + seg*32;
        float* dp = dlds + chl*144 + seg*36;
        #pragma unroll
        for (int j=0;j<4;j++){
          uint4 hv = *(uint4*)(hp + j*8);
          f32x4 d0 = *(const f32x4*)(dp + j*8);
          f32x4 d1 = *(const f32x4*)(dp + j*8 + 4);
          d0[0] += bf2f(hv.x&0xffff); d0[1] += bf2f(hv.x>>16);
          d0[2] += bf2f(hv.y&0xffff); d0[3] += bf2f(hv.y>>16);
          d1[0] += bf2f(hv.z&0xffff); d1[1] += bf2f(hv.z>>16);
          d1[2] += bf2f(hv.w&0xffff); d1[3] += bf2f(hv.w>>16);
          hv.x = (unsigned)f2bf(d0[0]) | ((unsigned)f2bf(d0[1])<<16);
          hv.y = (unsigned)f2bf(d0[2]) | ((unsigned)f2bf(d0[3])<<16);
          hv.z = (unsigned)f2bf(d1[0]) | ((unsigned)f2bf(d1[1])<<16);
          hv.w = (unsigned)f2bf(d1[2]) | ((unsigned)f2bf(d1[3])<<16);
          *(uint4*)(hp + j*8) = hv;
          *(f32x4*)(dp + j*8) = d0;
          *(f32x4*)(dp + j*8 + 4) = d1;
        }
      }
      __syncthreads();
      {
        int j = tid >> 1, hc = (tid & 1)*32;
        int js = (j>>5)*36 + (j&31);
        float s0 = 0.f, s1 = 0.f;
        #pragma unroll
        for (int c=0;c<32;c++){
          float v = dlds[(hc+c)*144 + js];
          s0 += v; s1 = fmaf(v, v, s1);
        }
        s0 += __shfl_xor(s0, 1, 64);
        s1 += __shfl_xor(s1, 1, 64);
        s0t += s0; s1t += s1;
      }
    }
    if (!(tid & 1)){
      float2* stP = stats + (size_t)blockIdx.y*BLq;
      stP[col0 + (tid >> 1)] = make_float2(s0t, s1t);
    }
  }
}

// ---------------- final gather ----------------
__global__ __launch_bounds__(256) void k_gather(const unsigned short* __restrict__ h,
    float* __restrict__ o){
  int idx = blockIdx.x*256 + threadIdx.x;
  int b = idx >> 8, c = idx & (Hq-1);
  o[idx] = bf2f(h[((size_t)b*Hq + c)*Lq + (Lq-1)]);
}

extern "C" void kernel_launch(void* const* d_in, const int* in_sizes, int n_in,
                              void* d_out, int out_size, void* d_ws, size_t ws_size,
                              hipStream_t stream) {
  (void)in_sizes; (void)n_in; (void)out_size; (void)ws_size;
  const float* x         = (const float*)d_in[0];
  const float* conv_w    = (const float*)d_in[1];
  const float* conv_b    = (const float*)d_in[2];
  const float* s4_norm_w = (const float*)d_in[3];
  const float* s4_norm_b = (const float*)d_in[4];
  const float* log_dt    = (const float*)d_in[5];
  const float* log_A_real= (const float*)d_in[6];
  const float* A_imag    = (const float*)d_in[7];
  const float* C_re      = (const float*)d_in[8];
  const float* C_im      = (const float*)d_in[9];
  const float* Dp        = (const float*)d_in[10];
  const float* s4_out_w  = (const float*)d_in[11];
  const float* s4_out_b  = (const float*)d_in[12];
  const float* ff_norm_w = (const float*)d_in[13];
  const float* ff_norm_b = (const float*)d_in[14];
  const float* ff_w1     = (const float*)d_in[15];
  const float* ff_b1     = (const float*)d_in[16];
  const float* ff_w2     = (const float*)d_in[17];
  const float* ff_b2     = (const float*)d_in[18];

  char* ws = (char*)d_ws;
  size_t off = 0;
  auto nxt = [&](size_t bytes){ size_t o = off; off = (off + bytes + 255) & ~(size_t)255; return o; };
  unsigned short* h = (unsigned short*)(ws + nxt((size_t)Bq*Hq*Lq*2));   // 32MB bf16
  float* mu     = (float*)(ws + nxt((size_t)BLq*4));
  float* rstd   = (float*)(ws + nxt((size_t)BLq*4));
  float* wre    = (float*)(ws + nxt((size_t)NBq*Hq*Nq*4));
  float* wim    = (float*)(ws + nxt((size_t)NBq*Hq*Nq*4));
  float* c2re   = (float*)(ws + nxt((size_t)NBq*Hq*Nq*4));
  float* c2im   = (float*)(ws + nxt((size_t)NBq*Hq*Nq*4));
  float* w64re  = (float*)(ws + nxt((size_t)NBq*Hq*Nq*4));
  float* w64im  = (float*)(ws + nxt((size_t)NBq*Hq*Nq*4));
  unsigned short* s4wb = (unsigned short*)(ws + nxt((size_t)NBq*F2q*Hq*2));
  unsigned short* f1b  = (unsigned short*)(ws + nxt((size_t)NBq*F2q*Hq*2));
  unsigned short* f2b  = (unsigned short*)(ws + nxt((size_t)NBq*Hq*F2q*2));
  unsigned short* Gm   = (unsigned short*)(ws + nxt((size_t)NBq*Hq*64*192*2)); // 24MB (x4)
  unsigned short* Wbar = (unsigned short*)(ws + nxt((size_t)NBq*Hq*128*64*2)); // 16MB (x4)
  unsigned short* U    = (unsigned short*)(ws + nxt((size_t)Hq*1024*64*2));    // 32MB (z only)
  unsigned short* Bb   = (unsigned short*)(ws + nxt((size_t)Hq*128*1024*2));   // 64MB
  unsigned short* ZBUF = (unsigned short*)(ws + nxt((size_t)BLq*F2q*2));       // 64MB
  // aliases (lifetime-checked):
  unsigned short* yT   = ZBUF;                               // transp -> gemm0
  unsigned short* ybuf = ZBUF + (size_t)16*1024*1024;        // ygemm -> transp
  unsigned short* z2T  = ZBUF;                               // gemm1 -> gemm2
  unsigned short* zT   = Bb + (size_t)16*1024*1024;          // lntransp -> gemm1 (Bb dead)
  float2* st0 = (float2*)Bb;                                 // gemm epi -> lnfin
  float2* st1 = st0 + BLq;

  k_convln<<<Bq*16, 256, 0, stream>>>(x, conv_w, conv_b, h, mu, rstd);
  k_s4pre<<<(NBq*Hq*Nq)/256, 256, 0, stream>>>(log_dt, log_A_real, A_imag, C_re, C_im,
                                               wre, wim, c2re, c2im);
  k_cvtw<<<(NBq*F2q*Hq)/256, 256, 0, stream>>>(s4_out_w, ff_w1, ff_w2, s4wb, f1b, f2b);
  k_s4mat<<<NBq*Hq, 64, 0, stream>>>(wre, wim, c2re, c2im, Dp, Gm, Wbar, w64re, w64im);

  for (int i=0;i<NBq;i++){
    const size_t po = (size_t)i*Hq*Nq;
    const unsigned short* Gmi   = Gm   + (size_t)i*Hq*64*192;
    const unsigned short* Wbari = Wbar + (size_t)i*Hq*128*64;
    // ---- S4 residual block ----
    k_prep<<<(Bq*Hq*Lq/8)/256, 256, 0, stream>>>(h, mu, rstd, s4_norm_w, s4_norm_b, U, i);
    k_bgemm<<<dim3(Hq, 8), 256, 0, stream>>>(Wbari, U, Bb);
    k_ygemm<<<dim3(Hq, Bq), 256, 0, stream>>>(Gmi, U, Bb, w64re+po, w64im+po, ybuf);
    k_transp<<<Bq*4*64, 256, 0, stream>>>(ybuf, yT);
    k_gemm<0,256><<<dim3(BLq/128, 2), 256, 0, stream>>>(
        yT, s4wb + (size_t)i*F2q*Hq, s4_out_b + (size_t)i*F2q, h, nullptr, st0);
    k_lnfin<<<BLq/256, 256, 0, stream>>>(st0, st1, mu, rstd);
    // ---- FF residual block ----
    k_lntransp<<<Bq*4*64, 256, 0, stream>>>(h, mu, rstd, ff_norm_w, ff_norm_b, zT, i);
    k_gemm<1,256><<<dim3(BLq/128, 4), 256, 0, stream>>>(
        zT, f1b + (size_t)i*F2q*Hq, ff_b1 + (size_t)i*F2q, nullptr, z2T, nullptr);
    k_gemm<2,512><<<dim3(BLq/128, 2), 256, 0, stream>>>(
        z2T, f2b + (size_t)i*Hq*F2q, ff_b2 + (size_t)i*Hq, h, nullptr, st0);
    if (i < NBq-1)
      k_lnfin<<<BLq/256, 256, 0, stream>>>(st0, st1, mu, rstd);
  }
  k_gather<<<(Bq*Hq)/256, 256, 0, stream>>>(h, (float*)d_out);
}